// Round 2
// baseline (653.011 us; speedup 1.0000x reference)
//
#include <hip/hip_runtime.h>
#include <stdint.h>

// Problem constants (fixed by setup_inputs): img (8,3,512,1024) f32, flo (8,2,512,1024) f32
constexpr int Nn = 8;
constexpr int Cc = 3;
constexpr int Hh = 512;
constexpr int Ww = 1024;
constexpr int HW = Hh * Ww;           // 524288
constexpr int NCHW = Nn * Cc * HW;    // 12582912

// Tiled LDS-scatter parameters
constexpr int TH = 32;                // owned output tile height
constexpr int TW = 64;                // owned output tile width
constexpr int R  = 4;                 // halo radius: tiled pass handles corners with
                                      // per-axis offset in [-R, R]; everything else goes
                                      // through the exact list-based fixup.
                                      // P(|N(0,1)| >= 4) ~ 6e-5 -> ~500 outlier px total.
constexpr int RH = TH + 2 * R;        // 40 source-region height
constexpr int RW = TW + 2 * R;        // 72 source-region width
constexpr int NPIX = RH * RW;         // 2880
constexpr int ITERS = (NPIX + 255) / 256;   // 12 (last 192 lanes of iter 11 masked)
constexpr int TILE_PIX = TH * TW;     // 2048

// LDS layout: 4 planar planes (c0,c1,c2,weight), plane stride PS words.
// Words [2048, 2112) of each plane are a per-lane dump region for masked
// corners (branchless scatter, conflict-free: word 2048+lane -> stride-1).
constexpr int PS = 2112;              // plane stride (words); byte stride 8448
constexpr int DUMP0 = 2048;           // first dump word within a plane
// asm offset immediates: plane1 = 8448 B, plane2 = 16896 B, plane3 = 25344 B
// LDS total: 4*2112*4 = 33792 B -> 4 blocks/CU (135168 <= 163840)

typedef float fvec4 __attribute__((ext_vector_type(4)));
typedef __attribute__((address_space(3))) float lds_f;

// -------------------------------------------------------------------------
// splat_tiled: one block per 32x64 output tile. All halo loads are issued
// up-front into registers (60 loads in flight < vmcnt limit 64) so HBM/L2
// latency is paid once per block, not once per iteration. The 16 per-pixel
// ds_add_f32 are ONE asm statement (one "memory" ordering point per pixel
// instead of 16 -- the 471us kernel's 16 clobbered asms pinned every load
// to its own iteration and serialized the whole wave).
// -------------------------------------------------------------------------
__global__ __launch_bounds__(256, 4) void splat_tiled(
        const float* __restrict__ img,
        const float* __restrict__ flo,
        float* __restrict__ out,                  // imgw at out, o at out+NCHW
        unsigned int* __restrict__ cnt,           // outlier count (workspace), may be null
        unsigned int* __restrict__ list,          // outlier pixel ids
        unsigned int cap) {
    __shared__ float acc[4 * PS];                 // 33792 B
    const int tid = threadIdx.x;
    {   // zero the real tile data (512 fvec4 per plane); dump words never read
        fvec4* a4 = (fvec4*)acc;
        fvec4 z = {0.f, 0.f, 0.f, 0.f};
        #pragma unroll
        for (int p = 0; p < 4; ++p) {
            a4[p * 528 + tid]       = z;          // 528 = PS/4
            a4[p * 528 + 256 + tid] = z;
        }
    }
    __syncthreads();

    const int tw0 = blockIdx.x * TW;
    const int th0 = blockIdx.y * TH;
    const int n   = blockIdx.z;
    const float* __restrict__ floy = flo + (size_t)(n * 2 + 0) * HW;  // indexes W axis
    const float* __restrict__ flox = flo + (size_t)(n * 2 + 1) * HW;  // indexes H axis
    const float* __restrict__ imgn = img + (size_t)n * Cc * HW;

    lds_f* A0 = (lds_f*)acc;
    const int dumpw = DUMP0 + (tid & 63);         // per-lane dump slot (stride-1)

    // ---- Phase A: issue ALL halo loads (clamped addresses; masking later) ----
    float sy[ITERS], sx[ITERS], u0[ITERS], u1[ITERS], u2[ITERS];
    #pragma unroll
    for (int it = 0; it < ITERS; ++it) {
        int i  = tid + 256 * it;
        int rh = i / RW;
        int rw = i - rh * RW;
        int h  = th0 - R + rh;
        int w  = tw0 - R + rw;
        int hc = h < 0 ? 0 : (h > Hh - 1 ? Hh - 1 : h);
        int wc = w < 0 ? 0 : (w > Ww - 1 ? Ww - 1 : w);
        int hwc = hc * Ww + wc;
        sy[it] = floy[hwc];
        sx[it] = flox[hwc];
        u0[it] = imgn[hwc];
        u1[it] = imgn[HW + hwc];
        u2[it] = imgn[2 * HW + hwc];
    }

    // ---- Phase B: compute + scatter, one fused asm per source pixel ----
    #pragma unroll
    for (int it = 0; it < ITERS; ++it) {
        int i  = tid + 256 * it;
        int rh = i / RW;
        int rw = i - rh * RW;
        int h  = th0 - R + rh;
        int w  = tw0 - R + rw;
        bool live = (i < NPIX) & (h >= 0) & (h < Hh) & (w >= 0) & (w < Ww);

        float y = sy[it], x = sx[it];
        float x1f = floorf(x), y1f = floorf(y);
        float fx = x - x1f, fy = y - y1f;
        float gx1 = fx * fx, gx2 = (fx - 1.0f) * (fx - 1.0f);
        float gy1 = fy * fy, gy2 = (fy - 1.0f) * (fy - 1.0f);
        float w11 = __expf(-(gx1 + gy1));
        float w12 = __expf(-(gx1 + gy2));
        float w21 = __expf(-(gx2 + gy1));
        float w22 = __expf(-(gx2 + gy2));

        // Corner offsets along h are {ox, ox+1}, along w are {oy, oy+1}.
        // The tiled pass may ONLY apply corners with per-axis offset in
        // [-R, R]; others belong to the fixup (exact partition, no double
        // count -- a far corner can still land inside this very tile).
        int ox = (int)x1f, oy = (int)y1f;
        bool okh1 = (ox >= -R)     & (ox <= R);
        bool okh2 = (ox + 1 >= -R) & (ox + 1 <= R);
        bool okw1 = (oy >= -R)     & (oy <= R);
        bool okw2 = (oy + 1 >= -R) & (oy + 1 <= R);

        int lh1 = ox + rh - R;      // local tile row of corner x1
        int lh2 = lh1 + 1;
        int lw1 = oy + rw - R;      // local tile col of corner y1
        int lw2 = lw1 + 1;

        float i0 = u0[it], i1 = u1[it], i2 = u2[it];

        auto caddr = [&](int lh, int lw, bool okc) -> lds_f* {
            bool ok = live & okc &
                      ((unsigned)lh < (unsigned)TH) & ((unsigned)lw < (unsigned)TW);
            int wi = ok ? (lh * TW + lw) : dumpw;
            return A0 + wi;
        };
        lds_f* a11 = caddr(lh1, lw1, okh1 & okw1);
        lds_f* a12 = caddr(lh1, lw2, okh1 & okw2);
        lds_f* a21 = caddr(lh2, lw1, okh2 & okw1);
        lds_f* a22 = caddr(lh2, lw2, okh2 & okw2);

        asm volatile(
            "ds_add_f32 %0, %4\n\t"
            "ds_add_f32 %0, %5 offset:8448\n\t"
            "ds_add_f32 %0, %6 offset:16896\n\t"
            "ds_add_f32 %0, %7 offset:25344\n\t"
            "ds_add_f32 %1, %8\n\t"
            "ds_add_f32 %1, %9 offset:8448\n\t"
            "ds_add_f32 %1, %10 offset:16896\n\t"
            "ds_add_f32 %1, %11 offset:25344\n\t"
            "ds_add_f32 %2, %12\n\t"
            "ds_add_f32 %2, %13 offset:8448\n\t"
            "ds_add_f32 %2, %14 offset:16896\n\t"
            "ds_add_f32 %2, %15 offset:25344\n\t"
            "ds_add_f32 %3, %16\n\t"
            "ds_add_f32 %3, %17 offset:8448\n\t"
            "ds_add_f32 %3, %18 offset:16896\n\t"
            "ds_add_f32 %3, %19 offset:25344"
            :: "v"(a11), "v"(a12), "v"(a21), "v"(a22),
               "v"(i0 * w11), "v"(i1 * w11), "v"(i2 * w11), "v"(w11),
               "v"(i0 * w12), "v"(i1 * w12), "v"(i2 * w12), "v"(w12),
               "v"(i0 * w21), "v"(i1 * w21), "v"(i2 * w21), "v"(w21),
               "v"(i0 * w22), "v"(i1 * w22), "v"(i2 * w22), "v"(w22)
            : "memory");

        // Inline outlier detection on OWNED pixels (replaces the full-image
        // rescan kernel). Owned <=> this block is the unique owner of (h,w).
        bool owned = ((unsigned)(rh - R) < (unsigned)TH) &
                     ((unsigned)(rw - R) < (unsigned)TW);
        bool outl = owned & ((x >= (float)R) | (x < -(float)R) |
                             (y >= (float)R) | (y < -(float)R));
        if (__builtin_expect(outl, 0)) {
            if (cnt != nullptr) {
                unsigned int id = atomicAdd(cnt, 1u);
                if (id < cap) list[id] = (unsigned int)(n * HW + (h * Ww + w));
            }
        }
    }
    __syncthreads();

    // ---- Epilogue: planar LDS -> coalesced nontemporal stores ----
    float* __restrict__ imgw  = out;
    float* __restrict__ o_out = out + NCHW;
    const size_t nb = (size_t)n * Cc * HW;
    const fvec4* a4 = (const fvec4*)acc;          // plane p at fvec4 index p*528
    #pragma unroll
    for (int itr = 0; itr < 2; ++itr) {           // 512 fvec4-pixels / 256 threads
        int q = tid + 256 * itr;
        fvec4 c0 = a4[q];
        fvec4 c1 = a4[528 + q];
        fvec4 c2 = a4[1056 + q];
        fvec4 wv = a4[1584 + q];
        int p0 = q * 4;
        int lh = p0 >> 6, lw = p0 & 63;
        size_t hw = (size_t)(th0 + lh) * Ww + (tw0 + lw);   // 16B aligned
        __builtin_nontemporal_store(c0, (fvec4*)(imgw + nb + hw));
        __builtin_nontemporal_store(c1, (fvec4*)(imgw + nb + HW + hw));
        __builtin_nontemporal_store(c2, (fvec4*)(imgw + nb + 2 * HW + hw));
        __builtin_nontemporal_store(wv, (fvec4*)(o_out + nb + hw));
        __builtin_nontemporal_store(wv, (fvec4*)(o_out + nb + HW + hw));
        __builtin_nontemporal_store(wv, (fvec4*)(o_out + nb + 2 * HW + hw));
    }
}

// Zero the outlier counter. A kernel (not hipMemsetAsync) so kernel_launch
// issues ONLY kernel launches -- nothing that can trip graph capture.
__global__ void zero_cnt(unsigned int* __restrict__ cnt) {
    if (threadIdx.x == 0 && blockIdx.x == 0) *cnt = 0u;
}

// Apply the corners the tiled pass missed (per-axis offset outside [-R, R])
// for one source pixel, with global atomics (CAS loop fine: ~500 px expected).
__device__ __forceinline__ void apply_outlier_px(
        const float* __restrict__ img, float* __restrict__ imgw,
        float* __restrict__ o_out, int n, int hw, float y, float x) {
    int h = hw >> 10;            // Ww = 1024
    int w = hw & (Ww - 1);
    float x1f = floorf(x), y1f = floorf(y);
    float fx = x - x1f, fy = y - y1f;
    float gx1 = fx * fx, gx2 = (fx - 1.0f) * (fx - 1.0f);
    float gy1 = fy * fy, gy2 = (fy - 1.0f) * (fy - 1.0f);
    float wts[4] = { __expf(-(gx1 + gy1)), __expf(-(gx1 + gy2)),
                     __expf(-(gx2 + gy1)), __expf(-(gx2 + gy2)) };
    int bx = (int)x1f, by = (int)y1f;
    int oh[4] = { bx, bx, bx + 1, bx + 1 };
    int ow[4] = { by, by + 1, by, by + 1 };
    float i0 = img[(size_t)(n * Cc + 0) * HW + hw];
    float i1 = img[(size_t)(n * Cc + 1) * HW + hw];
    float i2 = img[(size_t)(n * Cc + 2) * HW + hw];
    const size_t nb = (size_t)n * Cc * HW;
    #pragma unroll
    for (int c = 0; c < 4; ++c) {
        // Skip corners the tiled pass already applied (both axes in [-R,R]).
        if (oh[c] >= -R && oh[c] <= R && ow[c] >= -R && ow[c] <= R) continue;
        int ix = h + oh[c];
        int iy = w + ow[c];
        if (ix < 0 || ix >= Hh || iy < 0 || iy >= Ww) continue;
        int t = ix * Ww + iy;
        float wt = wts[c];
        atomicAdd(&imgw[nb + t], i0 * wt);
        atomicAdd(&imgw[nb + HW + t], i1 * wt);
        atomicAdd(&imgw[nb + 2 * HW + t], i2 * wt);
        atomicAdd(&o_out[nb + t], wt);
        atomicAdd(&o_out[nb + HW + t], wt);
        atomicAdd(&o_out[nb + 2 * HW + t], wt);
    }
}

// List-driven fixup. Falls back to an exact full rescan (float4-vectorized)
// only if the workspace list overflowed -- never expected for N(0,1) flow.
__global__ __launch_bounds__(256) void fixup(
        const float* __restrict__ img,
        const float* __restrict__ flo,
        float* __restrict__ out,
        const unsigned int* __restrict__ cnt,
        const unsigned int* __restrict__ list,
        unsigned int cap) {
    float* imgw  = out;
    float* o_out = out + NCHW;
    unsigned int total = *cnt;
    unsigned int gid = blockIdx.x * blockDim.x + threadIdx.x;
    unsigned int stride = gridDim.x * blockDim.x;
    if (total <= cap) {
        for (unsigned int j = gid; j < total; j += stride) {
            int idx = (int)list[j];
            int n  = idx / HW;
            int hw = idx - n * HW;
            float y = flo[(size_t)(n * 2 + 0) * HW + hw];
            float x = flo[(size_t)(n * 2 + 1) * HW + hw];
            apply_outlier_px(img, imgw, o_out, n, hw, y, x);
        }
    } else {
        for (unsigned int j = gid; j < (unsigned)(Nn * HW / 4); j += stride) {
            int n   = j / (HW / 4);
            int q   = j - n * (HW / 4);
            int hw0 = q * 4;
            const fvec4 y4 = *(const fvec4*)&flo[(size_t)(n * 2 + 0) * HW + hw0];
            const fvec4 x4 = *(const fvec4*)&flo[(size_t)(n * 2 + 1) * HW + hw0];
            #pragma unroll
            for (int k = 0; k < 4; ++k) {
                float x = x4[k], y = y4[k];
                if (x < (float)R && x >= -(float)R && y < (float)R && y >= -(float)R) continue;
                apply_outlier_px(img, imgw, o_out, n, hw0 + k, y, x);
            }
        }
    }
}

// No-workspace fallback: exact full rescan (float4), same math as fixup's else.
__global__ __launch_bounds__(256) void rescan_all(
        const float* __restrict__ img,
        const float* __restrict__ flo,
        float* __restrict__ out) {
    float* imgw  = out;
    float* o_out = out + NCHW;
    unsigned int j = blockIdx.x * blockDim.x + threadIdx.x;
    if (j >= (unsigned)(Nn * HW / 4)) return;
    int n   = j / (HW / 4);
    int q   = j - n * (HW / 4);
    int hw0 = q * 4;
    const fvec4 y4 = *(const fvec4*)&flo[(size_t)(n * 2 + 0) * HW + hw0];
    const fvec4 x4 = *(const fvec4*)&flo[(size_t)(n * 2 + 1) * HW + hw0];
    #pragma unroll
    for (int k = 0; k < 4; ++k) {
        float x = x4[k], y = y4[k];
        if (x < (float)R && x >= -(float)R && y < (float)R && y >= -(float)R) continue;
        apply_outlier_px(img, imgw, o_out, n, hw0 + k, y, x);
    }
}

extern "C" void kernel_launch(void* const* d_in, const int* in_sizes, int n_in,
                              void* d_out, int out_size, void* d_ws, size_t ws_size,
                              hipStream_t stream) {
    const float* img = (const float*)d_in[0];
    const float* flo = (const float*)d_in[1];
    float* out = (float*)d_out;

    dim3 block(256);
    dim3 grid(Ww / TW, Hh / TH, Nn);   // 16 x 16 x 8 = 2048 blocks

    bool have_ws = (d_ws != nullptr) && (ws_size >= 64);
    if (have_ws) {
        unsigned int* cnt  = (unsigned int*)d_ws;
        unsigned int* list = cnt + 1;
        size_t cap_sz = (ws_size - sizeof(unsigned int)) / sizeof(unsigned int);
        unsigned int cap = cap_sz > 0x3FFFFFu ? 0x3FFFFFu : (unsigned int)cap_sz;
        zero_cnt<<<1, 64, 0, stream>>>(cnt);
        splat_tiled<<<grid, block, 0, stream>>>(img, flo, out, cnt, list, cap);
        fixup<<<64, 256, 0, stream>>>(img, flo, out, cnt, list, cap);
    } else {
        splat_tiled<<<grid, block, 0, stream>>>(img, flo, out, nullptr, nullptr, 0u);
        rescan_all<<<(Nn * HW / 4 + 255) / 256, 256, 0, stream>>>(img, flo, out);
    }
}

// Round 3
// 228.305 us; speedup vs baseline: 2.8603x; 2.8603x over previous
//
#include <hip/hip_runtime.h>
#include <stdint.h>

// Problem constants (fixed by setup_inputs): img (8,3,512,1024) f32, flo (8,2,512,1024) f32
constexpr int Nn = 8;
constexpr int Cc = 3;
constexpr int Hh = 512;
constexpr int Ww = 1024;
constexpr int HW = Hh * Ww;           // 524288
constexpr int NCHW = Nn * Cc * HW;    // 12582912

// Tiled parameters. Measured model (R0 vs R2 A/B): LDS f32 atomics run at
// ~3.3 cyc per LANE-op serially (67M ops->352us, 94M ops->525us, all other
// pipes idle). Strategy: cut atomic lane-ops 4x -- per corner contribution,
// ONE ds_add_rtn_u32 counter bump allocates a slot; the 4 plane values go in
// with PLAIN ds_write_b32 (normal LDS throughput, not the atomic path).
constexpr int TH = 16;                // owned output tile height
constexpr int TW = 32;                // owned output tile width
constexpr int R  = 4;                 // tiled pass handles corners with per-axis
                                      // offset in [-R, R]; rest -> exact fixup.
constexpr int RH = TH + 2 * R;        // 24 source-region height
constexpr int RW = TW + 2 * R;        // 40 source-region width
constexpr int NPIX = RH * RW;         // 960
constexpr int ITERS = (NPIX + 255) / 256;   // 4
constexpr int TILE_PIX = TH * TW;     // 512
constexpr int SLOTS = 6;              // contributions/pixel: mean 4, Poisson-ish;
                                      // P(K>6)~11% of PIXELS -> ~4% of corners
                                      // overflow to exact ds_add_f32 planes.

typedef float fvec4 __attribute__((ext_vector_type(4)));
typedef __attribute__((address_space(3))) float lds_f;

// Overflow path: 4 hardware LDS f32 atomic adds (planes 2048B apart).
__device__ __forceinline__ void ds_fadd4(lds_f* p, float a, float b, float c, float d) {
    asm volatile(
        "ds_add_f32 %0, %1\n\t"
        "ds_add_f32 %0, %2 offset:2048\n\t"
        "ds_add_f32 %0, %3 offset:4096\n\t"
        "ds_add_f32 %0, %4 offset:6144"
        :: "v"(p), "v"(a), "v"(b), "v"(c), "v"(d) : "memory");
}

// -------------------------------------------------------------------------
// splat_tiled: one block per 16x32 output tile. Register-staged halo loads;
// per real corner: 1 atomic u32 bump + 4 plain LDS stores (slot), overflow
// -> f32 atomic planes. Epilogue: per-pixel slot sum + overflow + store.
// LDS: cnt 2KB + 4 slot planes 48KB + ovf 8KB = 58KB -> 2 blocks/CU.
// -------------------------------------------------------------------------
__global__ __launch_bounds__(256, 2) void splat_tiled(
        const float* __restrict__ img,
        const float* __restrict__ flo,
        float* __restrict__ out,                  // imgw at out, o at out+NCHW
        unsigned int* __restrict__ cnt,           // outlier count (workspace), may be null
        unsigned int* __restrict__ list,          // outlier pixel ids
        unsigned int cap) {
    __shared__ unsigned int s_cnt[TILE_PIX];          //  2 KB
    __shared__ float s_slot0[TILE_PIX * SLOTS];       // 12 KB
    __shared__ float s_slot1[TILE_PIX * SLOTS];       // 12 KB
    __shared__ float s_slot2[TILE_PIX * SLOTS];       // 12 KB
    __shared__ float s_slot3[TILE_PIX * SLOTS];       // 12 KB
    __shared__ float s_ovf[4 * TILE_PIX];             //  8 KB
    const int tid = threadIdx.x;
    #pragma unroll
    for (int i = tid; i < TILE_PIX; i += 256) s_cnt[i] = 0u;
    #pragma unroll
    for (int i = tid; i < 4 * TILE_PIX; i += 256) s_ovf[i] = 0.0f;
    __syncthreads();

    const int tw0 = blockIdx.x * TW;
    const int th0 = blockIdx.y * TH;
    const int n   = blockIdx.z;
    const float* __restrict__ floy = flo + (size_t)(n * 2 + 0) * HW;  // indexes W axis
    const float* __restrict__ flox = flo + (size_t)(n * 2 + 1) * HW;  // indexes H axis
    const float* __restrict__ imgn = img + (size_t)n * Cc * HW;

    // ---- Phase A: issue ALL halo loads (clamped addresses; masking later) ----
    float sy[ITERS], sx[ITERS], u0[ITERS], u1[ITERS], u2[ITERS];
    #pragma unroll
    for (int it = 0; it < ITERS; ++it) {
        int i  = tid + 256 * it;
        int ic = i < NPIX ? i : NPIX - 1;
        int rh = ic / RW;
        int rw = ic - rh * RW;
        int h  = th0 - R + rh;
        int w  = tw0 - R + rw;
        int hc = h < 0 ? 0 : (h > Hh - 1 ? Hh - 1 : h);
        int wc = w < 0 ? 0 : (w > Ww - 1 ? Ww - 1 : w);
        int hwc = hc * Ww + wc;
        sy[it] = floy[hwc];
        sx[it] = flox[hwc];
        u0[it] = imgn[hwc];
        u1[it] = imgn[HW + hwc];
        u2[it] = imgn[2 * HW + hwc];
    }

    // ---- Phase B: compute + slot-scatter ----
    #pragma unroll
    for (int it = 0; it < ITERS; ++it) {
        int i  = tid + 256 * it;
        int rh = i / RW;
        int rw = i - rh * RW;
        int h  = th0 - R + rh;
        int w  = tw0 - R + rw;
        bool live = (i < NPIX) & (h >= 0) & (h < Hh) & (w >= 0) & (w < Ww);

        float y = sy[it], x = sx[it];
        float x1f = floorf(x), y1f = floorf(y);
        float fx = x - x1f, fy = y - y1f;
        float gx1 = fx * fx, gx2 = (fx - 1.0f) * (fx - 1.0f);
        float gy1 = fy * fy, gy2 = (fy - 1.0f) * (fy - 1.0f);
        float w11 = __expf(-(gx1 + gy1));
        float w12 = __expf(-(gx1 + gy2));
        float w21 = __expf(-(gx2 + gy1));
        float w22 = __expf(-(gx2 + gy2));

        // Partition: tiled pass applies ONLY corners with per-axis offset in
        // [-R, R]; others -> fixup (exact, no double count).
        int ox = (int)x1f, oy = (int)y1f;
        bool okh1 = (ox >= -R)     & (ox <= R);
        bool okh2 = (ox + 1 >= -R) & (ox + 1 <= R);
        bool okw1 = (oy >= -R)     & (oy <= R);
        bool okw2 = (oy + 1 >= -R) & (oy + 1 <= R);

        int lh1 = ox + rh - R;
        int lh2 = lh1 + 1;
        int lw1 = oy + rw - R;
        int lw2 = lw1 + 1;

        float i0 = u0[it], i1 = u1[it], i2 = u2[it];

        auto corner = [&](int lh, int lw, bool okc, float wt) {
            bool ok = live & okc &
                      ((unsigned)lh < (unsigned)TH) & ((unsigned)lw < (unsigned)TW);
            if (ok) {
                int pix = lh * TW + lw;
                unsigned int idx = atomicAdd(&s_cnt[pix], 1u);   // ds_add_rtn_u32
                if (idx < (unsigned)SLOTS) {
                    int sb = pix * SLOTS + (int)idx;
                    s_slot0[sb] = i0 * wt;      // plain ds_write_b32 (cheap)
                    s_slot1[sb] = i1 * wt;
                    s_slot2[sb] = i2 * wt;
                    s_slot3[sb] = wt;
                } else {
                    ds_fadd4((lds_f*)s_ovf + pix, i0 * wt, i1 * wt, i2 * wt, wt);
                }
            }
        };
        corner(lh1, lw1, okh1 & okw1, w11);
        corner(lh1, lw2, okh1 & okw2, w12);
        corner(lh2, lw1, okh2 & okw1, w21);
        corner(lh2, lw2, okh2 & okw2, w22);

        // Outlier detection on OWNED pixels (feeds the list-based fixup).
        bool owned = ((unsigned)(rh - R) < (unsigned)TH) &
                     ((unsigned)(rw - R) < (unsigned)TW);
        bool outl = owned & ((x >= (float)R) | (x < -(float)R) |
                             (y >= (float)R) | (y < -(float)R));
        if (__builtin_expect(outl, 0)) {
            if (cnt != nullptr) {
                unsigned int id = atomicAdd(cnt, 1u);
                if (id < cap) list[id] = (unsigned int)(n * HW + (h * Ww + w));
            }
        }
    }
    __syncthreads();

    // ---- Epilogue: per-pixel slot sum + overflow, coalesced stores ----
    float* __restrict__ imgw  = out;
    float* __restrict__ o_out = out + NCHW;
    const size_t nb = (size_t)n * Cc * HW;
    #pragma unroll
    for (int itr = 0; itr < 2; ++itr) {           // 512 pixels / 256 threads
        int pix = tid + 256 * itr;
        unsigned int k = s_cnt[pix];
        if (k > (unsigned)SLOTS) k = SLOTS;
        float s0 = s_ovf[pix];
        float s1 = s_ovf[TILE_PIX + pix];
        float s2 = s_ovf[2 * TILE_PIX + pix];
        float s3 = s_ovf[3 * TILE_PIX + pix];
        int base = pix * SLOTS;
        #pragma unroll
        for (int j = 0; j < SLOTS; ++j) {
            if ((unsigned)j < k) {
                s0 += s_slot0[base + j];
                s1 += s_slot1[base + j];
                s2 += s_slot2[base + j];
                s3 += s_slot3[base + j];
            }
        }
        int lh = pix >> 5, lw = pix & 31;         // TW = 32
        size_t hw = (size_t)(th0 + lh) * Ww + (tw0 + lw);
        __builtin_nontemporal_store(s0, imgw + nb + hw);
        __builtin_nontemporal_store(s1, imgw + nb + HW + hw);
        __builtin_nontemporal_store(s2, imgw + nb + 2 * HW + hw);
        __builtin_nontemporal_store(s3, o_out + nb + hw);
        __builtin_nontemporal_store(s3, o_out + nb + HW + hw);
        __builtin_nontemporal_store(s3, o_out + nb + 2 * HW + hw);
    }
}

// Zero the outlier counter (kernel, not hipMemsetAsync: graph-capture safe).
__global__ void zero_cnt(unsigned int* __restrict__ cnt) {
    if (threadIdx.x == 0 && blockIdx.x == 0) *cnt = 0u;
}

// Apply the corners the tiled pass missed (per-axis offset outside [-R, R]).
__device__ __forceinline__ void apply_outlier_px(
        const float* __restrict__ img, float* __restrict__ imgw,
        float* __restrict__ o_out, int n, int hw, float y, float x) {
    int h = hw >> 10;            // Ww = 1024
    int w = hw & (Ww - 1);
    float x1f = floorf(x), y1f = floorf(y);
    float fx = x - x1f, fy = y - y1f;
    float gx1 = fx * fx, gx2 = (fx - 1.0f) * (fx - 1.0f);
    float gy1 = fy * fy, gy2 = (fy - 1.0f) * (fy - 1.0f);
    float wts[4] = { __expf(-(gx1 + gy1)), __expf(-(gx1 + gy2)),
                     __expf(-(gx2 + gy1)), __expf(-(gx2 + gy2)) };
    int bx = (int)x1f, by = (int)y1f;
    int oh[4] = { bx, bx, bx + 1, bx + 1 };
    int ow[4] = { by, by + 1, by, by + 1 };
    float i0 = img[(size_t)(n * Cc + 0) * HW + hw];
    float i1 = img[(size_t)(n * Cc + 1) * HW + hw];
    float i2 = img[(size_t)(n * Cc + 2) * HW + hw];
    const size_t nb = (size_t)n * Cc * HW;
    #pragma unroll
    for (int c = 0; c < 4; ++c) {
        if (oh[c] >= -R && oh[c] <= R && ow[c] >= -R && ow[c] <= R) continue;
        int ix = h + oh[c];
        int iy = w + ow[c];
        if (ix < 0 || ix >= Hh || iy < 0 || iy >= Ww) continue;
        int t = ix * Ww + iy;
        float wt = wts[c];
        atomicAdd(&imgw[nb + t], i0 * wt);
        atomicAdd(&imgw[nb + HW + t], i1 * wt);
        atomicAdd(&imgw[nb + 2 * HW + t], i2 * wt);
        atomicAdd(&o_out[nb + t], wt);
        atomicAdd(&o_out[nb + HW + t], wt);
        atomicAdd(&o_out[nb + 2 * HW + t], wt);
    }
}

// List-driven fixup; full-rescan fallback only if the list overflowed.
__global__ __launch_bounds__(256) void fixup(
        const float* __restrict__ img,
        const float* __restrict__ flo,
        float* __restrict__ out,
        const unsigned int* __restrict__ cnt,
        const unsigned int* __restrict__ list,
        unsigned int cap) {
    float* imgw  = out;
    float* o_out = out + NCHW;
    unsigned int total = *cnt;
    unsigned int gid = blockIdx.x * blockDim.x + threadIdx.x;
    unsigned int stride = gridDim.x * blockDim.x;
    if (total <= cap) {
        for (unsigned int j = gid; j < total; j += stride) {
            int idx = (int)list[j];
            int n  = idx / HW;
            int hw = idx - n * HW;
            float y = flo[(size_t)(n * 2 + 0) * HW + hw];
            float x = flo[(size_t)(n * 2 + 1) * HW + hw];
            apply_outlier_px(img, imgw, o_out, n, hw, y, x);
        }
    } else {
        for (unsigned int j = gid; j < (unsigned)(Nn * HW / 4); j += stride) {
            int n   = j / (HW / 4);
            int q   = j - n * (HW / 4);
            int hw0 = q * 4;
            const fvec4 y4 = *(const fvec4*)&flo[(size_t)(n * 2 + 0) * HW + hw0];
            const fvec4 x4 = *(const fvec4*)&flo[(size_t)(n * 2 + 1) * HW + hw0];
            #pragma unroll
            for (int k = 0; k < 4; ++k) {
                float x = x4[k], y = y4[k];
                if (x < (float)R && x >= -(float)R && y < (float)R && y >= -(float)R) continue;
                apply_outlier_px(img, imgw, o_out, n, hw0 + k, y, x);
            }
        }
    }
}

// No-workspace fallback: exact full rescan (float4), grid-stride.
__global__ __launch_bounds__(256) void rescan_all(
        const float* __restrict__ img,
        const float* __restrict__ flo,
        float* __restrict__ out) {
    float* imgw  = out;
    float* o_out = out + NCHW;
    unsigned int gid = blockIdx.x * blockDim.x + threadIdx.x;
    unsigned int stride = gridDim.x * blockDim.x;
    for (unsigned int j = gid; j < (unsigned)(Nn * HW / 4); j += stride) {
        int n   = j / (HW / 4);
        int q   = j - n * (HW / 4);
        int hw0 = q * 4;
        const fvec4 y4 = *(const fvec4*)&flo[(size_t)(n * 2 + 0) * HW + hw0];
        const fvec4 x4 = *(const fvec4*)&flo[(size_t)(n * 2 + 1) * HW + hw0];
        #pragma unroll
        for (int k = 0; k < 4; ++k) {
            float x = x4[k], y = y4[k];
            if (x < (float)R && x >= -(float)R && y < (float)R && y >= -(float)R) continue;
            apply_outlier_px(img, imgw, o_out, n, hw0 + k, y, x);
        }
    }
}

extern "C" void kernel_launch(void* const* d_in, const int* in_sizes, int n_in,
                              void* d_out, int out_size, void* d_ws, size_t ws_size,
                              hipStream_t stream) {
    const float* img = (const float*)d_in[0];
    const float* flo = (const float*)d_in[1];
    float* out = (float*)d_out;

    dim3 block(256);
    dim3 grid(Ww / TW, Hh / TH, Nn);   // 32 x 32 x 8 = 8192 blocks

    bool have_ws = (d_ws != nullptr) && (ws_size >= 64);
    if (have_ws) {
        unsigned int* cnt  = (unsigned int*)d_ws;
        unsigned int* list = cnt + 1;
        size_t cap_sz = (ws_size - sizeof(unsigned int)) / sizeof(unsigned int);
        unsigned int cap = cap_sz > 0x3FFFFFu ? 0x3FFFFFu : (unsigned int)cap_sz;
        zero_cnt<<<1, 64, 0, stream>>>(cnt);
        splat_tiled<<<grid, block, 0, stream>>>(img, flo, out, cnt, list, cap);
        fixup<<<64, 256, 0, stream>>>(img, flo, out, cnt, list, cap);
    } else {
        splat_tiled<<<grid, block, 0, stream>>>(img, flo, out, nullptr, nullptr, 0u);
        rescan_all<<<512, 256, 0, stream>>>(img, flo, out);
    }
}